// Round 6
// baseline (427.184 us; speedup 1.0000x reference)
//
#include <hip/hip_runtime.h>
#include <hip/hip_bf16.h>

// Problem constants
#define S_LEN   2048
#define HID     2560
#define NH      32
#define NKV     8
#define HD      128
#define QDIM    (NH*HD)    // 4096
#define KVDIM   (NKV*HD)   // 1024

typedef __attribute__((ext_vector_type(8))) short short8;   // 8 bf16 (4 VGPRs)
typedef __attribute__((ext_vector_type(4))) float f32x4;    // MFMA C/D frag

__device__ __forceinline__ unsigned short f2bf(float f) {
    unsigned u = __float_as_uint(f);
    u += 0x7fffu + ((u >> 16) & 1u);        // round-to-nearest-even
    return (unsigned short)(u >> 16);
}
__device__ __forceinline__ float bf2f(unsigned short s) {
    return __uint_as_float(((unsigned)s) << 16);
}
// packed f32x2 -> bf16x2 (v_cvt_pk_bf16_f32 on gfx950)
__device__ __forceinline__ unsigned pk2bf(float a, float b) {
    __hip_bfloat162 h = __float22bfloat162_rn(make_float2(a, b));
    union { __hip_bfloat162 h; unsigned u; } c; c.h = h; return c.u;
}
__device__ __forceinline__ void gload16(const void* g, void* l) {
    __builtin_amdgcn_global_load_lds(
        (const __attribute__((address_space(1))) unsigned int*)g,
        (__attribute__((address_space(3))) unsigned int*)l, 16, 0, 0);
}

// ---------------------------------------------------------------------------
// Fused fp32 -> bf16 converts: hs, Wq, Wk, Wv in one segmented launch.
// ---------------------------------------------------------------------------
#define N4_HS  (S_LEN*HID/4)        // 1310720
#define N4_WQ  (QDIM*HID/4)         // 2621440
#define N4_WKV (KVDIM*HID/4)        // 655360
__global__ __launch_bounds__(256) void cvt4(
    const float* __restrict__ hs, const float* __restrict__ Wq,
    const float* __restrict__ Wk, const float* __restrict__ Wv,
    unsigned short* __restrict__ hsB, unsigned short* __restrict__ WqB,
    unsigned short* __restrict__ WkB, unsigned short* __restrict__ WvB)
{
    int i = blockIdx.x * 256 + threadIdx.x;
    const float* s; unsigned short* d;
    if (i < N4_HS)                          { s = hs; d = hsB; }
    else if (i < N4_HS + N4_WQ)             { i -= N4_HS; s = Wq; d = WqB; }
    else if (i < N4_HS + N4_WQ + N4_WKV)    { i -= N4_HS + N4_WQ; s = Wk; d = WkB; }
    else                                    { i -= N4_HS + N4_WQ + N4_WKV; s = Wv; d = WvB; }
    float4 v = ((const float4*)s)[i];
    uint2 o;
    o.x = pk2bf(v.x, v.y); o.y = pk2bf(v.z, v.w);
    ((uint2*)d)[i] = o;
}

__global__ __launch_bounds__(256) void cvt_f32_bf16(
    const float* __restrict__ s, unsigned short* __restrict__ d, int n4)
{
    int i = blockIdx.x * 256 + threadIdx.x;
    if (i >= n4) return;
    float4 v = ((const float4*)s)[i];
    uint2 o;
    o.x = pk2bf(v.x, v.y); o.y = pk2bf(v.z, v.w);
    ((uint2*)d)[i] = o;
}

// ---------------------------------------------------------------------------
// Shared BK=64 GEMM core: 128x128 tile, 256 threads, 4 waves (2x2 of 64x64).
// XOR swizzle on the GLOBAL chunk; fragment reads apply the same XOR.
// ---------------------------------------------------------------------------
struct GemmRegs {
    f32x4 acc[4][4];
};
__device__ __forceinline__ void gemm_core(
    const unsigned short* A, const unsigned short* B, int Kd,
    unsigned short* As, unsigned short* Bs, GemmRegs& R,
    int rowA0, int rowB0, int tid)
{
    const int lane = tid & 63;
    const int l15 = lane & 15, l4 = lane >> 4;
    const int w = tid >> 6;
    const int wr = (w >> 1) * 64, wc = (w & 1) * 64;
    const int sw = l15 & 7;                 // read-side XOR swizzle

#pragma unroll
    for (int i = 0; i < 4; i++)
#pragma unroll
        for (int j = 0; j < 4; j++)
            R.acc[i][j] = (f32x4){0.f, 0.f, 0.f, 0.f};

    for (int k0 = 0; k0 < Kd; k0 += 64) {
        __syncthreads();
#pragma unroll
        for (int i = 0; i < 4; i++) {
            int tc = tid + i * 256;          // chunk 0..1023
            int r = tc >> 3, cl = tc & 7;
            int cg = cl ^ (r & 7);
            gload16(A + (size_t)(rowA0 + r) * Kd + k0 + cg * 8, &As[tc * 8]);
            gload16(B + (size_t)(rowB0 + r) * Kd + k0 + cg * 8, &Bs[tc * 8]);
        }
        __syncthreads();

#pragma unroll
        for (int ks = 0; ks < 2; ks++) {
            const int kc = (ks * 4 + l4) ^ sw;
            short8 af[4], bf[4];
#pragma unroll
            for (int i = 0; i < 4; i++)
                af[i] = *(const short8*)&As[(wr + i*16 + l15)*64 + kc*8];
#pragma unroll
            for (int j = 0; j < 4; j++)
                bf[j] = *(const short8*)&Bs[(wc + j*16 + l15)*64 + kc*8];
#pragma unroll
            for (int i = 0; i < 4; i++)
#pragma unroll
                for (int j = 0; j < 4; j++)
                    R.acc[i][j] = __builtin_amdgcn_mfma_f32_16x16x32_bf16(
                        af[i], bf[j], R.acc[i][j], 0, 0, 0);
        }
    }
}

// Generic GEMM: C[M,N] = A * B^T, fp32 or bf16 out.
__global__ __launch_bounds__(256) void gemm_bf16(
    const unsigned short* __restrict__ A, const unsigned short* __restrict__ B,
    float* __restrict__ Cf, unsigned short* __restrict__ Cb, int N, int Kd)
{
    __shared__ unsigned short As[128*64];
    __shared__ unsigned short Bs[128*64];
    const int tid = threadIdx.x;
    const int lane = tid & 63, w = tid >> 6;
    const int l15 = lane & 15, l4 = lane >> 4;
    const int wr = (w >> 1) * 64, wc = (w & 1) * 64;
    GemmRegs R;
    gemm_core(A, B, Kd, As, Bs, R, blockIdx.y * 128, blockIdx.x * 128, tid);

#pragma unroll
    for (int i = 0; i < 4; i++)
#pragma unroll
        for (int j = 0; j < 4; j++) {
            int row0 = blockIdx.y*128 + wr + i*16 + l4*4;
            int col  = blockIdx.x*128 + wc + j*16 + l15;
#pragma unroll
            for (int r = 0; r < 4; r++) {
                size_t off = (size_t)(row0 + r) * N + col;
                if (Cf) Cf[off] = R.acc[i][j][r];
                else    Cb[off] = f2bf(R.acc[i][j][r]);
            }
        }
}

// Fused QKV projection. bx<32 -> Q, <40 -> K, else V written TRANSPOSED as
// VT[kvh][d][s] (acc regs r=0..3 are consecutive s -> packed uint2 stores).
__global__ __launch_bounds__(256) void gemm_qkv(
    const unsigned short* __restrict__ A,
    const unsigned short* __restrict__ Wq, const unsigned short* __restrict__ Wk,
    const unsigned short* __restrict__ Wv,
    unsigned short* __restrict__ Qo, unsigned short* __restrict__ Ko,
    unsigned short* __restrict__ VTo)
{
    __shared__ unsigned short As[128*64];
    __shared__ unsigned short Bs[128*64];
    const int bx = blockIdx.x;              // 0..47
    const unsigned short* B;
    if (bx < 32)      B = Wq + (size_t)bx*128*HID;
    else if (bx < 40) B = Wk + (size_t)(bx-32)*128*HID;
    else              B = Wv + (size_t)(bx-40)*128*HID;

    const int tid = threadIdx.x;
    const int lane = tid & 63, w = tid >> 6;
    const int l15 = lane & 15, l4 = lane >> 4;
    const int wr = (w >> 1) * 64, wc = (w & 1) * 64;
    GemmRegs R;
    gemm_core(A, B, HID, As, Bs, R, blockIdx.y * 128, 0, tid);

    if (bx < 40) {
        unsigned short* C; int ldc, cb;
        if (bx < 32) { C = Qo; ldc = QDIM;  cb = bx*128; }
        else         { C = Ko; ldc = KVDIM; cb = (bx-32)*128; }
#pragma unroll
        for (int i = 0; i < 4; i++)
#pragma unroll
            for (int j = 0; j < 4; j++) {
                int row0 = blockIdx.y*128 + wr + i*16 + l4*4;
                int col  = cb + wc + j*16 + l15;
#pragma unroll
                for (int r = 0; r < 4; r++)
                    C[(size_t)(row0 + r) * ldc + col] = f2bf(R.acc[i][j][r]);
            }
    } else {
        const int cbase = (bx - 40) * 128;
#pragma unroll
        for (int i = 0; i < 4; i++)
#pragma unroll
            for (int j = 0; j < 4; j++) {
                int col  = cbase + wc + j*16 + l15;            // v-dim 0..1023
                int row0 = blockIdx.y*128 + wr + i*16 + l4*4;  // s
                int kvhh = col >> 7, d = col & 127;
                unsigned short* p = VTo + (size_t)kvhh*HD*S_LEN + (size_t)d*S_LEN + row0;
                uint2 pk;
                pk.x = pk2bf(R.acc[i][j][0], R.acc[i][j][1]);
                pk.y = pk2bf(R.acc[i][j][2], R.acc[i][j][3]);
                *(uint2*)p = pk;
            }
    }
}

// ---------------------------------------------------------------------------
// RMSNorm (per 128-d head vector) + RoPE, in place on bf16. (unchanged)
// ---------------------------------------------------------------------------
__global__ __launch_bounds__(256) void rmsnorm_rope_bf16(
    unsigned short* __restrict__ X, const float* __restrict__ w,
    const float* __restrict__ ct, const float* __restrict__ st, int nheads)
{
    int wid  = (blockIdx.x * blockDim.x + threadIdx.x) >> 6;
    int lane = threadIdx.x & 63;
    int s = wid / nheads;
    int h = wid - s * nheads;
    unsigned short* x = X + (size_t)s * (nheads * HD) + h * HD;

    float x1 = bf2f(x[lane]);
    float x2 = bf2f(x[lane + 64]);
    float ss = x1*x1 + x2*x2;
#pragma unroll
    for (int off = 32; off > 0; off >>= 1) ss += __shfl_xor(ss, off, 64);
    float r = rsqrtf(ss * (1.0f/128.0f) + 1e-6f);
    float n1 = x1 * r * w[lane];
    float n2 = x2 * r * w[lane + 64];
    float c1 = ct[s*HD + lane],      s1 = st[s*HD + lane];
    float c2 = ct[s*HD + lane + 64], s2 = st[s*HD + lane + 64];
    x[lane]      = f2bf(n1*c1 - n2*s1);
    x[lane + 64] = f2bf(n2*c2 + n1*s2);
}

// ---------------------------------------------------------------------------
// Flash attention v4: bf16 MFMA, causal, GQA, fixed-max softmax.
// Block = (64 q-rows, one q-head), 4 waves; wave w owns q-rows w*16..+15.
// KV tile 64. V comes PRE-TRANSPOSED (VT[kvh][d][s]) so both K and V are
// staged via global_load_lds with XOR chunk swizzle -> zero staging VALU.
// Grid = 32 qtiles x 32 heads (descending size); LDS 42.2 KB -> 3 blocks/CU.
// ---------------------------------------------------------------------------
__global__ __launch_bounds__(256, 3) void flash_mfma(
    const unsigned short* __restrict__ Q, const unsigned short* __restrict__ K,
    const unsigned short* __restrict__ VT, unsigned short* __restrict__ O)
{
    const int qt = 31 - (int)blockIdx.x;     // big blocks first
    const int h = blockIdx.y, kvh = h >> 2;
    const int tid = threadIdx.x;
    const int w = tid >> 6, lane = tid & 63;
    const int l15 = lane & 15, l4 = lane >> 4;
    const int q0 = qt * 64;

    __shared__ unsigned short Ks[64*128];    // swizzled chunks, 16 KB
    __shared__ unsigned short Vt[128*64];    // V^T [d][kv], swizzled, 16 KB
    __shared__ unsigned short Ps[4*16*72];   // per-wave P strips [q][kv], 9 KB
    __shared__ float Lw[4][16];              // per-wave row sums

    const float scale2 = 0.08838834764831845f * 1.4426950408889634f;
    const float M2 = 17.3f;                  // fixed max: |score|<=11.32 -> *log2e < 16.4
    unsigned short* Pw = &Ps[w * 16 * 72];
    const unsigned short* VTh = VT + (size_t)kvh * HD * S_LEN;

    // Q fragments: B-operand layout = lane l15 -> q-row, l4*8 -> k
    short8 qa[4];
    {
        const unsigned short* qg = Q + (size_t)(q0 + w*16 + l15) * QDIM + h * HD;
#pragma unroll
        for (int ka = 0; ka < 4; ka++)
            qa[ka] = *(const short8*)(qg + ka*32 + l4*8);
    }

    const f32x4 zero = {0.f, 0.f, 0.f, 0.f};
    f32x4 accO[8];
#pragma unroll
    for (int j = 0; j < 8; j++) accO[j] = zero;
    float lsum = 0.f;

    for (int t = 0; t <= qt; t++) {
        const int c0 = t * 64;
        __syncthreads();
        {   // stage K tile [64 kv][128 k]: 1024 chunks, XOR swizzle
#pragma unroll
            for (int i = 0; i < 4; i++) {
                int tc = tid + i * 256;
                int r = tc >> 4, cl = tc & 15;
                int cg = cl ^ (r & 7);
                gload16(K + (size_t)(c0 + r) * KVDIM + kvh * HD + cg * 8,
                        &Ks[tc * 8]);
            }
        }
        {   // stage V^T tile [128 d][64 kv]: 1024 chunks, XOR swizzle
#pragma unroll
            for (int i = 0; i < 4; i++) {
                int tc = tid + i * 256;
                int r = tc >> 3, cl = tc & 7;
                int cg = cl ^ (r & 7);
                gload16(VTh + (size_t)r * S_LEN + c0 + cg * 8, &Vt[tc * 8]);
            }
        }
        __syncthreads();

        // ---- S^T = K Q^T : C rows = kv (mt*16 + l4*4+r), cols = q (l15) ----
        f32x4 sc[4];
#pragma unroll
        for (int mt = 0; mt < 4; mt++) sc[mt] = zero;
#pragma unroll
        for (int ka = 0; ka < 4; ka++) {
#pragma unroll
            for (int mt = 0; mt < 4; mt++) {
                int row = mt*16 + l15;
                int cs = (ka*4 + l4) ^ (row & 7);
                short8 kb = *(const short8*)&Ks[row*128 + cs*8];
                sc[mt] = __builtin_amdgcn_mfma_f32_16x16x32_bf16(kb, qa[ka], sc[mt], 0, 0, 0);
            }
        }

        // ---- fixed-max softmax + causal mask + packed P store ----
        const int qglob = q0 + w*16 + l15;
        const bool diag = (t == qt);
#pragma unroll
        for (int mt = 0; mt < 4; mt++) {
            float pv[4];
#pragma unroll
            for (int r = 0; r < 4; r++) {
                int kvg = c0 + mt*16 + l4*4 + r;
                float e = __builtin_amdgcn_exp2f(fmaf(sc[mt][r], scale2, -M2));
                pv[r] = (!diag || kvg <= qglob) ? e : 0.f;
                lsum += pv[r];
            }
            uint2 pk;
            pk.x = pk2bf(pv[0], pv[1]);
            pk.y = pk2bf(pv[2], pv[3]);
            *(uint2*)&Pw[l15*72 + mt*16 + l4*4] = pk;   // P[q][kv]
        }

        // ---- PV: accO[dt] += P x V^T (A=P, B=V^T) ----
#pragma unroll
        for (int ks = 0; ks < 2; ks++) {
            short8 pf = *(const short8*)&Pw[l15*72 + ks*32 + l4*8];
            const int cs = (ks*4 + l4) ^ (l15 & 7);   // (dt*16+l15)&7 == l15&7
#pragma unroll
            for (int dt = 0; dt < 8; dt++) {
                short8 vf = *(const short8*)&Vt[(dt*16 + l15)*64 + cs*8];
                accO[dt] = __builtin_amdgcn_mfma_f32_16x16x32_bf16(pf, vf, accO[dt], 0, 0, 0);
            }
        }
    }

    // ---- finalize l: reduce over the 4 l4 groups ----
    lsum += __shfl_xor(lsum, 16, 64);
    lsum += __shfl_xor(lsum, 32, 64);
    if (l4 == 0) Lw[w][l15] = lsum;          // wave-lockstep LDS exchange
    f32x4 linv;
#pragma unroll
    for (int r = 0; r < 4; r++) linv[r] = 1.0f / Lw[w][l4*4 + r];

    // epilogue: O rows = q (l4*4+r), cols = d (dt*16+l15)
#pragma unroll
    for (int dt = 0; dt < 8; dt++)
#pragma unroll
        for (int r = 0; r < 4; r++) {
            int row_l = w*16 + l4*4 + r;
            O[(size_t)(q0 + row_l) * QDIM + h*HD + dt*16 + l15] =
                f2bf(accO[dt][r] * linv[r]);
        }
}

// ---------------------------------------------------------------------------
extern "C" void kernel_launch(void* const* d_in, const int* in_sizes, int n_in,
                              void* d_out, int out_size, void* d_ws, size_t ws_size,
                              hipStream_t stream)
{
    const float* hs   = (const float*)d_in[0];
    const float* cosb = (const float*)d_in[1];
    const float* sinb = (const float*)d_in[2];
    const float* Wq   = (const float*)d_in[3];
    const float* Wk   = (const float*)d_in[4];
    const float* Wv   = (const float*)d_in[5];
    const float* Wo   = (const float*)d_in[6];
    const float* qw   = (const float*)d_in[7];
    const float* kw   = (const float*)d_in[8];
    float* out = (float*)d_out;

    // Workspace layout (peak 79.7 MB):
    //   hsB 0..10.49M | WqB 10.49..31.46M | WkB 31.46..36.70M | WvB 36.70..41.94M
    //   KB 41.94..46.14M, VT 46.14..50.33M  (inside WoB slot; dead after flash)
    //   WoB 41.94..62.91M (converted AFTER flash, overwrites KB/VT)
    //   QB 62.91..79.69M | CB 18.87..35.65M (aliases WqB tail + WkB; dead after
    //   QKV GEMM, written by flash, read by out-proj)
    char* ws = (char*)d_ws;
    unsigned short* hsB = (unsigned short*)(ws);
    unsigned short* WqB = (unsigned short*)(ws + 10485760);
    unsigned short* WkB = (unsigned short*)(ws + 31457280);
    unsigned short* WvB = (unsigned short*)(ws + 36700160);
    unsigned short* KB  = (unsigned short*)(ws + 41943040);
    unsigned short* VT  = (unsigned short*)(ws + 46137344);
    unsigned short* WoB = (unsigned short*)(ws + 41943040);
    unsigned short* QB  = (unsigned short*)(ws + 62914560);
    unsigned short* CB  = (unsigned short*)(ws + 18874368);

    // converts for hs + Wq + Wk + Wv (one launch)
    {
        int n4 = N4_HS + N4_WQ + 2 * N4_WKV;
        cvt4<<<(n4+255)/256, 256, 0, stream>>>(hs, Wq, Wk, Wv, hsB, WqB, WkB, WvB);
    }

    // fused QKV projection (Q,K row-major bf16; V transposed)
    gemm_qkv<<<dim3(48, S_LEN/128), 256, 0, stream>>>(hsB, WqB, WkB, WvB, QB, KB, VT);

    // norm + rope (in place, bf16; V needs none)
    rmsnorm_rope_bf16<<<S_LEN*NH/4,  256, 0, stream>>>(QB, qw, cosb, sinb, NH);
    rmsnorm_rope_bf16<<<S_LEN*NKV/4, 256, 0, stream>>>(KB, kw, cosb, sinb, NKV);

    // attention: 32 qtiles (descending) x 32 heads
    flash_mfma<<<dim3(32, NH), 256, 0, stream>>>(QB, KB, VT, CB);

    // convert Wo now (KB/VT dead; WoB overwrites their slot)
    cvt_f32_bf16<<<(HID*QDIM/4+255)/256, 256, 0, stream>>>(Wo, WoB, HID*QDIM/4);

    // output projection (fp32 out)
    gemm_bf16<<<dim3(HID/128, S_LEN/128), 256, 0, stream>>>(CB, WoB, out, nullptr, HID, QDIM);
}

// Round 7
// 385.828 us; speedup vs baseline: 1.1072x; 1.1072x over previous
//
#include <hip/hip_runtime.h>
#include <hip/hip_bf16.h>

// Problem constants
#define S_LEN   2048
#define HID     2560
#define NH      32
#define NKV     8
#define HD      128
#define QDIM    (NH*HD)    // 4096
#define KVDIM   (NKV*HD)   // 1024

typedef __attribute__((ext_vector_type(8))) short short8;   // 8 bf16 (4 VGPRs)
typedef __attribute__((ext_vector_type(4))) float f32x4;    // MFMA C/D frag

__device__ __forceinline__ unsigned short f2bf(float f) {
    unsigned u = __float_as_uint(f);
    u += 0x7fffu + ((u >> 16) & 1u);        // round-to-nearest-even
    return (unsigned short)(u >> 16);
}
__device__ __forceinline__ float bf2f(unsigned short s) {
    return __uint_as_float(((unsigned)s) << 16);
}
// packed f32x2 -> bf16x2 (v_cvt_pk_bf16_f32 on gfx950)
__device__ __forceinline__ unsigned pk2bf(float a, float b) {
    __hip_bfloat162 h = __float22bfloat162_rn(make_float2(a, b));
    union { __hip_bfloat162 h; unsigned u; } c; c.h = h; return c.u;
}
__device__ __forceinline__ void gload16(const void* g, void* l) {
    __builtin_amdgcn_global_load_lds(
        (const __attribute__((address_space(1))) unsigned int*)g,
        (__attribute__((address_space(3))) unsigned int*)l, 16, 0, 0);
}

// ---------------------------------------------------------------------------
// Fused fp32 -> bf16 converts: hs, Wq, Wk, Wv in one segmented launch.
// ---------------------------------------------------------------------------
#define N4_HS  (S_LEN*HID/4)        // 1310720
#define N4_WQ  (QDIM*HID/4)         // 2621440
#define N4_WKV (KVDIM*HID/4)        // 655360
__global__ __launch_bounds__(256) void cvt4(
    const float* __restrict__ hs, const float* __restrict__ Wq,
    const float* __restrict__ Wk, const float* __restrict__ Wv,
    unsigned short* __restrict__ hsB, unsigned short* __restrict__ WqB,
    unsigned short* __restrict__ WkB, unsigned short* __restrict__ WvB)
{
    int i = blockIdx.x * 256 + threadIdx.x;
    const float* s; unsigned short* d;
    if (i < N4_HS)                          { s = hs; d = hsB; }
    else if (i < N4_HS + N4_WQ)             { i -= N4_HS; s = Wq; d = WqB; }
    else if (i < N4_HS + N4_WQ + N4_WKV)    { i -= N4_HS + N4_WQ; s = Wk; d = WkB; }
    else                                    { i -= N4_HS + N4_WQ + N4_WKV; s = Wv; d = WvB; }
    float4 v = ((const float4*)s)[i];
    uint2 o;
    o.x = pk2bf(v.x, v.y); o.y = pk2bf(v.z, v.w);
    ((uint2*)d)[i] = o;
}

__global__ __launch_bounds__(256) void cvt_f32_bf16(
    const float* __restrict__ s, unsigned short* __restrict__ d, int n4)
{
    int i = blockIdx.x * 256 + threadIdx.x;
    if (i >= n4) return;
    float4 v = ((const float4*)s)[i];
    uint2 o;
    o.x = pk2bf(v.x, v.y); o.y = pk2bf(v.z, v.w);
    ((uint2*)d)[i] = o;
}

// ---------------------------------------------------------------------------
// BK=64 GEMM core (128x128): 256 threads, 4 waves (2x2 of 64x64).
// XOR swizzle on the GLOBAL chunk; fragment reads apply the same XOR.
// ---------------------------------------------------------------------------
struct GemmRegs {
    f32x4 acc[4][4];
};
__device__ __forceinline__ void gemm_core(
    const unsigned short* A, const unsigned short* B, int Kd,
    unsigned short* As, unsigned short* Bs, GemmRegs& R,
    int rowA0, int rowB0, int tid)
{
    const int lane = tid & 63;
    const int l15 = lane & 15, l4 = lane >> 4;
    const int w = tid >> 6;
    const int wr = (w >> 1) * 64, wc = (w & 1) * 64;
    const int sw = l15 & 7;                 // read-side XOR swizzle

#pragma unroll
    for (int i = 0; i < 4; i++)
#pragma unroll
        for (int j = 0; j < 4; j++)
            R.acc[i][j] = (f32x4){0.f, 0.f, 0.f, 0.f};

    for (int k0 = 0; k0 < Kd; k0 += 64) {
        __syncthreads();
#pragma unroll
        for (int i = 0; i < 4; i++) {
            int tc = tid + i * 256;          // chunk 0..1023
            int r = tc >> 3, cl = tc & 7;
            int cg = cl ^ (r & 7);
            gload16(A + (size_t)(rowA0 + r) * Kd + k0 + cg * 8, &As[tc * 8]);
            gload16(B + (size_t)(rowB0 + r) * Kd + k0 + cg * 8, &Bs[tc * 8]);
        }
        __syncthreads();

#pragma unroll
        for (int ks = 0; ks < 2; ks++) {
            const int kc = (ks * 4 + l4) ^ sw;
            short8 af[4], bf[4];
#pragma unroll
            for (int i = 0; i < 4; i++)
                af[i] = *(const short8*)&As[(wr + i*16 + l15)*64 + kc*8];
#pragma unroll
            for (int j = 0; j < 4; j++)
                bf[j] = *(const short8*)&Bs[(wc + j*16 + l15)*64 + kc*8];
#pragma unroll
            for (int i = 0; i < 4; i++)
#pragma unroll
                for (int j = 0; j < 4; j++)
                    R.acc[i][j] = __builtin_amdgcn_mfma_f32_16x16x32_bf16(
                        af[i], bf[j], R.acc[i][j], 0, 0, 0);
        }
    }
}

// Fused QKV projection. bx<32 -> Q, <40 -> K, else V written TRANSPOSED as
// VT[kvh][d][s] (acc regs r=0..3 are consecutive s -> packed uint2 stores).
__global__ __launch_bounds__(256) void gemm_qkv(
    const unsigned short* __restrict__ A,
    const unsigned short* __restrict__ Wq, const unsigned short* __restrict__ Wk,
    const unsigned short* __restrict__ Wv,
    unsigned short* __restrict__ Qo, unsigned short* __restrict__ Ko,
    unsigned short* __restrict__ VTo)
{
    __shared__ unsigned short As[128*64];
    __shared__ unsigned short Bs[128*64];
    const int bx = blockIdx.x;              // 0..47
    const unsigned short* B;
    if (bx < 32)      B = Wq + (size_t)bx*128*HID;
    else if (bx < 40) B = Wk + (size_t)(bx-32)*128*HID;
    else              B = Wv + (size_t)(bx-40)*128*HID;

    const int tid = threadIdx.x;
    const int lane = tid & 63, w = tid >> 6;
    const int l15 = lane & 15, l4 = lane >> 4;
    const int wr = (w >> 1) * 64, wc = (w & 1) * 64;
    GemmRegs R;
    gemm_core(A, B, HID, As, Bs, R, blockIdx.y * 128, 0, tid);

    if (bx < 40) {
        unsigned short* C; int ldc, cb;
        if (bx < 32) { C = Qo; ldc = QDIM;  cb = bx*128; }
        else         { C = Ko; ldc = KVDIM; cb = (bx-32)*128; }
#pragma unroll
        for (int i = 0; i < 4; i++)
#pragma unroll
            for (int j = 0; j < 4; j++) {
                int row0 = blockIdx.y*128 + wr + i*16 + l4*4;
                int col  = cb + wc + j*16 + l15;
#pragma unroll
                for (int r = 0; r < 4; r++)
                    C[(size_t)(row0 + r) * ldc + col] = f2bf(R.acc[i][j][r]);
            }
    } else {
        const int cbase = (bx - 40) * 128;
#pragma unroll
        for (int i = 0; i < 4; i++)
#pragma unroll
            for (int j = 0; j < 4; j++) {
                int col  = cbase + wc + j*16 + l15;            // v-dim 0..1023
                int row0 = blockIdx.y*128 + wr + i*16 + l4*4;  // s
                int kvhh = col >> 7, d = col & 127;
                unsigned short* p = VTo + (size_t)kvhh*HD*S_LEN + (size_t)d*S_LEN + row0;
                uint2 pk;
                pk.x = pk2bf(R.acc[i][j][0], R.acc[i][j][1]);
                pk.y = pk2bf(R.acc[i][j][2], R.acc[i][j][3]);
                *(uint2*)p = pk;
            }
    }
}

// ---------------------------------------------------------------------------
// Out-projection GEMM: 64x128 tiles -> grid (20,32) = 640 blocks (2.5/CU
// schedule util ~83% vs 320-block 62.5%). 4 waves as 2x2 of 32x64.
// ---------------------------------------------------------------------------
__global__ __launch_bounds__(256) void gemm_out(
    const unsigned short* __restrict__ A, const unsigned short* __restrict__ B,
    float* __restrict__ C, int N, int Kd)
{
    __shared__ unsigned short As[64*64];    // 8 KB
    __shared__ unsigned short Bs[128*64];   // 16 KB
    const int tid = threadIdx.x;
    const int lane = tid & 63, w = tid >> 6;
    const int l15 = lane & 15, l4 = lane >> 4;
    const int wr = (w >> 1) * 32, wc = (w & 1) * 64;
    const int rowA0 = blockIdx.y * 64, rowB0 = blockIdx.x * 128;
    const int sw = l15 & 7;

    f32x4 acc[2][4];
#pragma unroll
    for (int i = 0; i < 2; i++)
#pragma unroll
        for (int j = 0; j < 4; j++) acc[i][j] = (f32x4){0.f, 0.f, 0.f, 0.f};

    for (int k0 = 0; k0 < Kd; k0 += 64) {
        __syncthreads();
#pragma unroll
        for (int i = 0; i < 2; i++) {       // A: 512 chunks
            int tc = tid + i * 256;
            int r = tc >> 3, cl = tc & 7;
            int cg = cl ^ (r & 7);
            gload16(A + (size_t)(rowA0 + r) * Kd + k0 + cg * 8, &As[tc * 8]);
        }
#pragma unroll
        for (int i = 0; i < 4; i++) {       // B: 1024 chunks
            int tc = tid + i * 256;
            int r = tc >> 3, cl = tc & 7;
            int cg = cl ^ (r & 7);
            gload16(B + (size_t)(rowB0 + r) * Kd + k0 + cg * 8, &Bs[tc * 8]);
        }
        __syncthreads();

#pragma unroll
        for (int ks = 0; ks < 2; ks++) {
            const int kc = (ks * 4 + l4) ^ sw;
            short8 af[2], bf[4];
#pragma unroll
            for (int i = 0; i < 2; i++)
                af[i] = *(const short8*)&As[(wr + i*16 + l15)*64 + kc*8];
#pragma unroll
            for (int j = 0; j < 4; j++)
                bf[j] = *(const short8*)&Bs[(wc + j*16 + l15)*64 + kc*8];
#pragma unroll
            for (int i = 0; i < 2; i++)
#pragma unroll
                for (int j = 0; j < 4; j++)
                    acc[i][j] = __builtin_amdgcn_mfma_f32_16x16x32_bf16(
                        af[i], bf[j], acc[i][j], 0, 0, 0);
        }
    }

#pragma unroll
    for (int i = 0; i < 2; i++)
#pragma unroll
        for (int j = 0; j < 4; j++) {
            int row0 = rowA0 + wr + i*16 + l4*4;
            int col  = rowB0 + wc + j*16 + l15;
#pragma unroll
            for (int r = 0; r < 4; r++)
                C[(size_t)(row0 + r) * N + col] = acc[i][j][r];
        }
}

// ---------------------------------------------------------------------------
// RMSNorm (per 128-d head vector) + RoPE, in place on bf16. (unchanged)
// ---------------------------------------------------------------------------
__global__ __launch_bounds__(256) void rmsnorm_rope_bf16(
    unsigned short* __restrict__ X, const float* __restrict__ w,
    const float* __restrict__ ct, const float* __restrict__ st, int nheads)
{
    int wid  = (blockIdx.x * blockDim.x + threadIdx.x) >> 6;
    int lane = threadIdx.x & 63;
    int s = wid / nheads;
    int h = wid - s * nheads;
    unsigned short* x = X + (size_t)s * (nheads * HD) + h * HD;

    float x1 = bf2f(x[lane]);
    float x2 = bf2f(x[lane + 64]);
    float ss = x1*x1 + x2*x2;
#pragma unroll
    for (int off = 32; off > 0; off >>= 1) ss += __shfl_xor(ss, off, 64);
    float r = rsqrtf(ss * (1.0f/128.0f) + 1e-6f);
    float n1 = x1 * r * w[lane];
    float n2 = x2 * r * w[lane + 64];
    float c1 = ct[s*HD + lane],      s1 = st[s*HD + lane];
    float c2 = ct[s*HD + lane + 64], s2 = st[s*HD + lane + 64];
    x[lane]      = f2bf(n1*c1 - n2*s1);
    x[lane + 64] = f2bf(n2*c2 + n1*s2);
}

// ---------------------------------------------------------------------------
// Flash attention v5: bf16 MFMA, causal, GQA, fixed-max softmax.
// Balanced pairing grid: block pb does Q-tiles (31-pb) then pb -> every
// block = exactly 33 tile-units; 512 blocks, all co-resident (2/CU).
// V PRE-TRANSPOSED (VT[kvh][d][s]); K and V both staged via global_load_lds
// with XOR chunk swizzle -> zero staging VALU. Packed pk2bf P stores.
// ---------------------------------------------------------------------------
__global__ __launch_bounds__(256, 3) void flash_mfma(
    const unsigned short* __restrict__ Q, const unsigned short* __restrict__ K,
    const unsigned short* __restrict__ VT, unsigned short* __restrict__ O)
{
    const int pb = blockIdx.x;               // 0..15
    const int h = blockIdx.y, kvh = h >> 2;
    const int tid = threadIdx.x;
    const int w = tid >> 6, lane = tid & 63;
    const int l15 = lane & 15, l4 = lane >> 4;

    __shared__ unsigned short Ks[64*128];    // swizzled chunks, 16 KB
    __shared__ unsigned short Vt[128*64];    // V^T [d][kv], swizzled, 16 KB
    __shared__ unsigned short Ps[4*16*72];   // per-wave P strips [q][kv], 9 KB
    __shared__ float Lw[4][16];              // per-wave row sums

    const float scale2 = 0.08838834764831845f * 1.4426950408889634f;
    const float M2 = 17.3f;                  // fixed max: |score| <= 11.32
    unsigned short* Pw = &Ps[w * 16 * 72];
    const unsigned short* VTh = VT + (size_t)kvh * HD * S_LEN;

#pragma unroll 1
    for (int phase = 0; phase < 2; phase++) {
        const int qt = phase ? pb : (31 - pb);
        const int q0 = qt * 64;

        // Q fragments: B-operand layout = lane l15 -> q-row, l4*8 -> k
        short8 qa[4];
        {
            const unsigned short* qg = Q + (size_t)(q0 + w*16 + l15) * QDIM + h * HD;
#pragma unroll
            for (int ka = 0; ka < 4; ka++)
                qa[ka] = *(const short8*)(qg + ka*32 + l4*8);
        }

        const f32x4 zero = {0.f, 0.f, 0.f, 0.f};
        f32x4 accO[8];
#pragma unroll
        for (int j = 0; j < 8; j++) accO[j] = zero;
        float lsum = 0.f;

        for (int t = 0; t <= qt; t++) {
            const int c0 = t * 64;
            __syncthreads();
            {   // stage K tile [64 kv][128 k]: 1024 chunks, XOR swizzle
#pragma unroll
                for (int i = 0; i < 4; i++) {
                    int tc = tid + i * 256;
                    int r = tc >> 4, cl = tc & 15;
                    int cg = cl ^ (r & 7);
                    gload16(K + (size_t)(c0 + r) * KVDIM + kvh * HD + cg * 8,
                            &Ks[tc * 8]);
                }
            }
            {   // stage V^T tile [128 d][64 kv]: 1024 chunks, XOR swizzle
#pragma unroll
                for (int i = 0; i < 4; i++) {
                    int tc = tid + i * 256;
                    int r = tc >> 3, cl = tc & 7;
                    int cg = cl ^ (r & 7);
                    gload16(VTh + (size_t)r * S_LEN + c0 + cg * 8, &Vt[tc * 8]);
                }
            }
            __syncthreads();

            // ---- S^T = K Q^T : C rows = kv (mt*16+l4*4+r), cols = q (l15)
            f32x4 sc[4];
#pragma unroll
            for (int mt = 0; mt < 4; mt++) sc[mt] = zero;
#pragma unroll
            for (int ka = 0; ka < 4; ka++) {
#pragma unroll
                for (int mt = 0; mt < 4; mt++) {
                    int row = mt*16 + l15;
                    int cs = (ka*4 + l4) ^ (row & 7);
                    short8 kb = *(const short8*)&Ks[row*128 + cs*8];
                    sc[mt] = __builtin_amdgcn_mfma_f32_16x16x32_bf16(kb, qa[ka], sc[mt], 0, 0, 0);
                }
            }

            // ---- fixed-max softmax + causal mask + packed P store ----
            const int qglob = q0 + w*16 + l15;
            const bool diag = (t == qt);
#pragma unroll
            for (int mt = 0; mt < 4; mt++) {
                float pv[4];
#pragma unroll
                for (int r = 0; r < 4; r++) {
                    int kvg = c0 + mt*16 + l4*4 + r;
                    float e = __builtin_amdgcn_exp2f(fmaf(sc[mt][r], scale2, -M2));
                    pv[r] = (!diag || kvg <= qglob) ? e : 0.f;
                    lsum += pv[r];
                }
                uint2 pk;
                pk.x = pk2bf(pv[0], pv[1]);
                pk.y = pk2bf(pv[2], pv[3]);
                *(uint2*)&Pw[l15*72 + mt*16 + l4*4] = pk;   // P[q][kv]
            }

            // ---- PV: accO[dt] += P x V^T (A=P, B=V^T) ----
#pragma unroll
            for (int ks = 0; ks < 2; ks++) {
                short8 pf = *(const short8*)&Pw[l15*72 + ks*32 + l4*8];
                const int cs = (ks*4 + l4) ^ (l15 & 7);   // (dt*16+l15)&7 == l15&7
#pragma unroll
                for (int dt = 0; dt < 8; dt++) {
                    short8 vf = *(const short8*)&Vt[(dt*16 + l15)*64 + cs*8];
                    accO[dt] = __builtin_amdgcn_mfma_f32_16x16x32_bf16(pf, vf, accO[dt], 0, 0, 0);
                }
            }
        }

        // ---- finalize l: reduce over the 4 l4 groups ----
        lsum += __shfl_xor(lsum, 16, 64);
        lsum += __shfl_xor(lsum, 32, 64);
        if (l4 == 0) Lw[w][l15] = lsum;      // wave-lockstep LDS exchange
        f32x4 linv;
#pragma unroll
        for (int r = 0; r < 4; r++) linv[r] = 1.0f / Lw[w][l4*4 + r];

        // epilogue: O rows = q (l4*4+r), cols = d (dt*16+l15)
#pragma unroll
        for (int dt = 0; dt < 8; dt++)
#pragma unroll
            for (int r = 0; r < 4; r++) {
                int row_l = w*16 + l4*4 + r;
                O[(size_t)(q0 + row_l) * QDIM + h*HD + dt*16 + l15] =
                    f2bf(accO[dt][r] * linv[r]);
            }
    }
}

// ---------------------------------------------------------------------------
extern "C" void kernel_launch(void* const* d_in, const int* in_sizes, int n_in,
                              void* d_out, int out_size, void* d_ws, size_t ws_size,
                              hipStream_t stream)
{
    const float* hs   = (const float*)d_in[0];
    const float* cosb = (const float*)d_in[1];
    const float* sinb = (const float*)d_in[2];
    const float* Wq   = (const float*)d_in[3];
    const float* Wk   = (const float*)d_in[4];
    const float* Wv   = (const float*)d_in[5];
    const float* Wo   = (const float*)d_in[6];
    const float* qw   = (const float*)d_in[7];
    const float* kw   = (const float*)d_in[8];
    float* out = (float*)d_out;

    // Workspace layout (peak 79.7 MB):
    //   hsB 0..10.49M | WqB 10.49..31.46M | WkB 31.46..36.70M | WvB 36.70..41.94M
    //   KB 41.94..46.14M, VT 46.14..50.33M  (inside WoB slot; dead after flash)
    //   WoB 41.94..62.91M (converted AFTER flash, overwrites KB/VT)
    //   QB 62.91..79.69M | CB 18.87..35.65M (aliases WqB tail + WkB; dead after
    //   QKV GEMM, written by flash, read by out-proj)
    char* ws = (char*)d_ws;
    unsigned short* hsB = (unsigned short*)(ws);
    unsigned short* WqB = (unsigned short*)(ws + 10485760);
    unsigned short* WkB = (unsigned short*)(ws + 31457280);
    unsigned short* WvB = (unsigned short*)(ws + 36700160);
    unsigned short* KB  = (unsigned short*)(ws + 41943040);
    unsigned short* VT  = (unsigned short*)(ws + 46137344);
    unsigned short* WoB = (unsigned short*)(ws + 41943040);
    unsigned short* QB  = (unsigned short*)(ws + 62914560);
    unsigned short* CB  = (unsigned short*)(ws + 18874368);

    // converts for hs + Wq + Wk + Wv (one launch)
    {
        int n4 = N4_HS + N4_WQ + 2 * N4_WKV;
        cvt4<<<(n4+255)/256, 256, 0, stream>>>(hs, Wq, Wk, Wv, hsB, WqB, WkB, WvB);
    }

    // fused QKV projection (Q,K row-major bf16; V transposed)
    gemm_qkv<<<dim3(48, S_LEN/128), 256, 0, stream>>>(hsB, WqB, WkB, WvB, QB, KB, VT);

    // norm + rope (in place, bf16; V needs none)
    rmsnorm_rope_bf16<<<S_LEN*NH/4,  256, 0, stream>>>(QB, qw, cosb, sinb, NH);
    rmsnorm_rope_bf16<<<S_LEN*NKV/4, 256, 0, stream>>>(KB, kw, cosb, sinb, NKV);

    // attention: 16 balanced pair-blocks x 32 heads (512 uniform blocks)
    flash_mfma<<<dim3(16, NH), 256, 0, stream>>>(QB, KB, VT, CB);

    // convert Wo now (KB/VT dead; WoB overwrites their slot)
    cvt_f32_bf16<<<(HID*QDIM/4+255)/256, 256, 0, stream>>>(Wo, WoB, HID*QDIM/4);

    // output projection (fp32 out), 64x128 tiles -> 640 blocks
    gemm_out<<<dim3(HID/128, S_LEN/64), 256, 0, stream>>>(CB, WoB, out, HID, QDIM);
}